// Round 4
// baseline (5598.985 us; speedup 1.0000x reference)
//
#include <hip/hip_runtime.h>
#include <hip/hip_bf16.h>

typedef __hip_bfloat16 bf16;

constexpr int Nn = 100000;   // nodes
constexpr int Ee = 640000;   // edges
constexpr int Pp = 640000;   // pos entries
constexpr int Gg = 128;      // graphs
constexpr int Ll = 3;        // layers
#define Dd 128
#define BN_EPS 1e-5f

__device__ __forceinline__ float b2f(bf16 x) { return __bfloat162float(x); }
__device__ __forceinline__ bf16 f2b(float x) { return __float2bfloat16(x); }

union U8 { uint4 u; bf16 h[8]; };
union U4 { ushort4 u; bf16 h[4]; };

__device__ __forceinline__ float bnf(float x, float g, float b, float m, float v) {
  return (x - m) * (1.0f / sqrtf(v + BN_EPS)) * g + b;
}

// -------- estart[e] = lower_bound(pos_batch, e), e in [0, E] --------
__global__ void k_estart(const int* __restrict__ pos_batch, int* __restrict__ estart) {
  int e = blockIdx.x * blockDim.x + threadIdx.x;
  if (e > Ee) return;
  int lo = 0, hi = Pp;
  while (lo < hi) { int mid = (lo + hi) >> 1; if (pos_batch[mid] < e) lo = mid + 1; else hi = mid; }
  estart[e] = lo;
}

__global__ void k_init_vn(const float* __restrict__ vn_emb, float* __restrict__ vn) {
  int gid = blockIdx.x * blockDim.x + threadIdx.x;
  if (gid >= Gg * 128) return;
  vn[gid] = vn_emb[gid & 127];
}

// -------- h_in = node_emb[x_node] + vn[batch]  (layer 0); bf16 store --------
__global__ void k_hin0(const int* __restrict__ x_node, const float* __restrict__ node_emb,
                       const float* __restrict__ vn, const int* __restrict__ batch,
                       bf16* __restrict__ h_in) {
  int gid = blockIdx.x * blockDim.x + threadIdx.x;   // over N*16 groups of 8
  if (gid >= Nn * 16) return;
  int n = gid >> 4, c = gid & 15;
  int x = x_node[n], b = batch[n];
  float4 a0 = ((const float4*)node_emb)[x * 32 + c * 2];
  float4 a1 = ((const float4*)node_emb)[x * 32 + c * 2 + 1];
  float4 v0 = ((const float4*)vn)[b * 32 + c * 2];
  float4 v1 = ((const float4*)vn)[b * 32 + c * 2 + 1];
  U8 o;
  o.h[0] = f2b(a0.x + v0.x); o.h[1] = f2b(a0.y + v0.y);
  o.h[2] = f2b(a0.z + v0.z); o.h[3] = f2b(a0.w + v0.w);
  o.h[4] = f2b(a1.x + v1.x); o.h[5] = f2b(a1.y + v1.y);
  o.h[6] = f2b(a1.z + v1.z); o.h[7] = f2b(a1.w + v1.w);
  ((uint4*)h_in)[gid] = o.u;
}

// -------- h_in += vn[batch]  (layers 1..) in-place --------
__global__ void k_hin(const float* __restrict__ vn, const int* __restrict__ batch,
                      bf16* __restrict__ h_in) {
  int gid = blockIdx.x * blockDim.x + threadIdx.x;
  if (gid >= Nn * 16) return;
  int n = gid >> 4, c = gid & 15;
  U8 a; a.u = ((const uint4*)h_in)[gid];
  int b = batch[n];
  float4 v0 = ((const float4*)vn)[b * 32 + c * 2];
  float4 v1 = ((const float4*)vn)[b * 32 + c * 2 + 1];
  U8 o;
  o.h[0] = f2b(b2f(a.h[0]) + v0.x); o.h[1] = f2b(b2f(a.h[1]) + v0.y);
  o.h[2] = f2b(b2f(a.h[2]) + v0.z); o.h[3] = f2b(b2f(a.h[3]) + v0.w);
  o.h[4] = f2b(b2f(a.h[4]) + v1.x); o.h[5] = f2b(b2f(a.h[5]) + v1.y);
  o.h[6] = f2b(b2f(a.h[6]) + v1.z); o.h[7] = f2b(b2f(a.h[7]) + v1.w);
  ((uint4*)h_in)[gid] = o.u;
}

// -------- fused edge kernel (recomputes z per tile):
// zpool = segsum(z_init[pos_index]*pos_enc); z = relu(bn2(relu(bn1(zpool))@zeW+zeb))
// msg = relu(h_in[src] + eattr@We + z@Wp + be + bp); agg[dst] += msg
__global__ __launch_bounds__(256) void k_edge_fused(
    const int* __restrict__ estart, const int* __restrict__ pos_index,
    const float* __restrict__ pos_enc, const float* __restrict__ z_init,
    const float* __restrict__ ze_bn1, const float* __restrict__ ze_W,
    const float* __restrict__ ze_b, const float* __restrict__ ze_bn2,
    const float* __restrict__ eattr, const int* __restrict__ src,
    const int* __restrict__ dst, const bf16* __restrict__ h_in,
    const float* __restrict__ Wp, const float* __restrict__ We,
    const float* __restrict__ be, const float* __restrict__ bp,
    float* __restrict__ agg) {
  __shared__ alignas(16) float As[64][132];
  __shared__ alignas(16) float Bs[32][132];
  __shared__ float Ea[64][8];
  __shared__ alignas(16) float Ws[7][128];
  int tid = threadIdx.x;
  int tx = tid & 31, ty = tid >> 5;
  int e0 = blockIdx.x * 64;

  if (tid < 224) {             // We: 7x128 f32 = 224 float4
    int r = tid >> 5, c4 = tid & 31;
    *(float4*)&Ws[r][c4 * 4] = ((const float4*)We)[tid];
  }
  for (int idx = tid; idx < 448; idx += 256) {
    int r = idx / 7, c = idx % 7;
    Ea[r][c] = eattr[(e0 + r) * 7 + c];
  }
  // zpool: thread -> edge r = tid>>2, 32-col chunk cc = tid&3
  {
    int r = tid >> 2, cc = tid & 3;
    int e = e0 + r;
    int ps = estart[e], pe = estart[e + 1];
    float acc[32];
    #pragma unroll
    for (int j = 0; j < 32; ++j) acc[j] = 0.f;
    for (int p = ps; p < pe; ++p) {
      int idx = pos_index[p];
      float w = pos_enc[p];
      #pragma unroll
      for (int q = 0; q < 8; ++q) {
        float4 z4 = ((const float4*)z_init)[idx * 32 + cc * 8 + q];
        acc[q * 4 + 0] = fmaf(w, z4.x, acc[q * 4 + 0]);
        acc[q * 4 + 1] = fmaf(w, z4.y, acc[q * 4 + 1]);
        acc[q * 4 + 2] = fmaf(w, z4.z, acc[q * 4 + 2]);
        acc[q * 4 + 3] = fmaf(w, z4.w, acc[q * 4 + 3]);
      }
    }
    #pragma unroll
    for (int q = 0; q < 8; ++q) {
      int col = cc * 32 + q * 4;
      float4 g = *(const float4*)&ze_bn1[col];
      float4 b = *(const float4*)&ze_bn1[128 + col];
      float4 m = *(const float4*)&ze_bn1[256 + col];
      float4 v = *(const float4*)&ze_bn1[384 + col];
      As[r][col + 0] = fmaxf(0.f, bnf(acc[q * 4 + 0], g.x, b.x, m.x, v.x));
      As[r][col + 1] = fmaxf(0.f, bnf(acc[q * 4 + 1], g.y, b.y, m.y, v.y));
      As[r][col + 2] = fmaxf(0.f, bnf(acc[q * 4 + 2], g.z, b.z, m.z, v.z));
      As[r][col + 3] = fmaxf(0.f, bnf(acc[q * 4 + 3], g.w, b.w, m.w, v.w));
    }
  }
  __syncthreads();
  // accE = Ea @ We
  float accE[8][4];
  #pragma unroll
  for (int i = 0; i < 8; ++i)
    #pragma unroll
    for (int j = 0; j < 4; ++j) accE[i][j] = 0.f;
  #pragma unroll
  for (int k = 0; k < 7; ++k) {
    float4 b4 = *(const float4*)&Ws[k][tx * 4];
    #pragma unroll
    for (int i = 0; i < 8; ++i) {
      float a = Ea[ty + 8 * i][k];
      accE[i][0] += a * b4.x; accE[i][1] += a * b4.y;
      accE[i][2] += a * b4.z; accE[i][3] += a * b4.w;
    }
  }
  // GEMM1: acc1 = relu(bn1(zpool)) @ ze_W
  float acc1[8][4];
  #pragma unroll
  for (int i = 0; i < 8; ++i)
    #pragma unroll
    for (int j = 0; j < 4; ++j) acc1[i][j] = 0.f;
  for (int kc = 0; kc < 4; ++kc) {
    #pragma unroll
    for (int i = 0; i < 4; ++i) {
      int fl = tid + i * 256;
      int r = fl >> 5, c4 = fl & 31;
      *(float4*)&Bs[r][c4 * 4] = ((const float4*)ze_W)[(kc * 32 + r) * 32 + c4];
    }
    __syncthreads();
    #pragma unroll
    for (int k = 0; k < 32; ++k) {
      float4 b4 = *(const float4*)&Bs[k][tx * 4];
      #pragma unroll
      for (int i = 0; i < 8; ++i) {
        float a = As[ty + 8 * i][kc * 32 + k];
        acc1[i][0] += a * b4.x; acc1[i][1] += a * b4.y;
        acc1[i][2] += a * b4.z; acc1[i][3] += a * b4.w;
      }
    }
    __syncthreads();
  }
  // z tile = relu(bn2(acc1 + ze_b)) -> overwrite As (own elements only)
  {
    float4 zb = *(const float4*)&ze_b[tx * 4];
    float4 g  = *(const float4*)&ze_bn2[tx * 4];
    float4 bb = *(const float4*)&ze_bn2[128 + tx * 4];
    float4 m  = *(const float4*)&ze_bn2[256 + tx * 4];
    float4 vv = *(const float4*)&ze_bn2[384 + tx * 4];
    #pragma unroll
    for (int i = 0; i < 8; ++i) {
      As[ty + 8 * i][tx * 4 + 0] = fmaxf(0.f, bnf(acc1[i][0] + zb.x, g.x, bb.x, m.x, vv.x));
      As[ty + 8 * i][tx * 4 + 1] = fmaxf(0.f, bnf(acc1[i][1] + zb.y, g.y, bb.y, m.y, vv.y));
      As[ty + 8 * i][tx * 4 + 2] = fmaxf(0.f, bnf(acc1[i][2] + zb.z, g.z, bb.z, m.z, vv.z));
      As[ty + 8 * i][tx * 4 + 3] = fmaxf(0.f, bnf(acc1[i][3] + zb.w, g.w, bb.w, m.w, vv.w));
    }
  }
  __syncthreads();
  // GEMM2: accE += z @ Wp
  for (int kc = 0; kc < 4; ++kc) {
    #pragma unroll
    for (int i = 0; i < 4; ++i) {
      int fl = tid + i * 256;
      int r = fl >> 5, c4 = fl & 31;
      *(float4*)&Bs[r][c4 * 4] = ((const float4*)Wp)[(kc * 32 + r) * 32 + c4];
    }
    __syncthreads();
    #pragma unroll
    for (int k = 0; k < 32; ++k) {
      float4 b4 = *(const float4*)&Bs[k][tx * 4];
      #pragma unroll
      for (int i = 0; i < 8; ++i) {
        float a = As[ty + 8 * i][kc * 32 + k];
        accE[i][0] += a * b4.x; accE[i][1] += a * b4.y;
        accE[i][2] += a * b4.z; accE[i][3] += a * b4.w;
      }
    }
    __syncthreads();
  }
  // epilogue
  int col = tx * 4;
  float4 bea = *(const float4*)&be[col];
  float4 bpa = *(const float4*)&bp[col];
  float bias[4] = {bea.x + bpa.x, bea.y + bpa.y, bea.z + bpa.z, bea.w + bpa.w};
  #pragma unroll
  for (int i = 0; i < 8; ++i) {
    int e = e0 + ty + 8 * i;
    int s = src[e], d2 = dst[e];
    U4 h4; h4.u = ((const ushort4*)h_in)[s * 32 + tx];
    #pragma unroll
    for (int j = 0; j < 4; ++j) {
      float mj = fmaxf(0.f, accE[i][j] + bias[j] + b2f(h4.h[j]));
      atomicAdd(&agg[d2 * Dd + col + j], mj);
    }
  }
}

// -------- fused node MLP: x=(1+eps)*h_in+agg; t=relu(bn(x@W1+b1)); out=bn2(t@W2+b2)[,relu]
// writes bf16 into h_in for l<L-1, f32 into d_out for last layer
__global__ __launch_bounds__(256) void k_mlp_fused(
    const bf16* __restrict__ h_in, const float* __restrict__ agg,
    const float* __restrict__ eps_arr, int l,
    const float* __restrict__ W1, const float* __restrict__ b1, const float* __restrict__ bn,
    const float* __restrict__ W2, const float* __restrict__ b2, const float* __restrict__ bnp,
    int is_last, bf16* __restrict__ out_b, float* __restrict__ out_f) {
  __shared__ alignas(16) float As[64 * 132];   // phase2: reused as bf16 Ts[64][264]
  __shared__ alignas(16) float Bs[4224];       // phase1: [16][264]; phase2: [32][132]
  bf16* Ts = (bf16*)As;
  int tid = threadIdx.x;
  int tx = tid & 31, ty = tid >> 5;
  int r0 = blockIdx.x * 64;
  float epsv = 1.0f + eps_arr[l];
  // phase A: stage x into As
  #pragma unroll
  for (int i = 0; i < 4; ++i) {
    int fl = tid + i * 256;
    int r = fl >> 4, c = fl & 15;
    int row = r0 + r;
    float v[8] = {0.f, 0.f, 0.f, 0.f, 0.f, 0.f, 0.f, 0.f};
    if (row < Nn) {
      U8 hh; hh.u = ((const uint4*)h_in)[row * 16 + c];
      float4 g0 = ((const float4*)agg)[row * 32 + c * 2];
      float4 g1 = ((const float4*)agg)[row * 32 + c * 2 + 1];
      v[0] = epsv * b2f(hh.h[0]) + g0.x; v[1] = epsv * b2f(hh.h[1]) + g0.y;
      v[2] = epsv * b2f(hh.h[2]) + g0.z; v[3] = epsv * b2f(hh.h[3]) + g0.w;
      v[4] = epsv * b2f(hh.h[4]) + g1.x; v[5] = epsv * b2f(hh.h[5]) + g1.y;
      v[6] = epsv * b2f(hh.h[6]) + g1.z; v[7] = epsv * b2f(hh.h[7]) + g1.w;
    }
    #pragma unroll
    for (int j = 0; j < 8; ++j) As[r * 132 + c * 8 + j] = v[j];
  }
  __syncthreads();
  // GEMM1: 64x128 @ 128x256 -> acc[8][8]; k-chunks of 16
  float acc[8][8];
  #pragma unroll
  for (int i = 0; i < 8; ++i)
    #pragma unroll
    for (int j = 0; j < 8; ++j) acc[i][j] = 0.f;
  for (int kc = 0; kc < 8; ++kc) {
    #pragma unroll
    for (int i = 0; i < 4; ++i) {
      int fl = tid + i * 256;
      int r = fl >> 6, c4 = fl & 63;
      *(float4*)&Bs[r * 264 + c4 * 4] = ((const float4*)W1)[(kc * 16 + r) * 64 + c4];
    }
    __syncthreads();
    #pragma unroll
    for (int k = 0; k < 16; ++k) {
      float4 bA = *(const float4*)&Bs[k * 264 + tx * 8];
      float4 bB = *(const float4*)&Bs[k * 264 + tx * 8 + 4];
      #pragma unroll
      for (int i = 0; i < 8; ++i) {
        float a = As[(ty + 8 * i) * 132 + kc * 16 + k];
        acc[i][0] += a * bA.x; acc[i][1] += a * bA.y;
        acc[i][2] += a * bA.z; acc[i][3] += a * bA.w;
        acc[i][4] += a * bB.x; acc[i][5] += a * bB.y;
        acc[i][6] += a * bB.z; acc[i][7] += a * bB.w;
      }
    }
    __syncthreads();
  }
  // t = relu(bn(acc + b1)) -> Ts (bf16, reusing As memory)
  {
    float4 b1a = *(const float4*)&b1[tx * 8];       float4 b1b = *(const float4*)&b1[tx * 8 + 4];
    float4 ga  = *(const float4*)&bn[tx * 8];       float4 gb  = *(const float4*)&bn[tx * 8 + 4];
    float4 ba  = *(const float4*)&bn[256 + tx * 8]; float4 bb  = *(const float4*)&bn[256 + tx * 8 + 4];
    float4 ma  = *(const float4*)&bn[512 + tx * 8]; float4 mb  = *(const float4*)&bn[512 + tx * 8 + 4];
    float4 va  = *(const float4*)&bn[768 + tx * 8]; float4 vb  = *(const float4*)&bn[768 + tx * 8 + 4];
    #pragma unroll
    for (int i = 0; i < 8; ++i) {
      U8 o;
      o.h[0] = f2b(fmaxf(0.f, bnf(acc[i][0] + b1a.x, ga.x, ba.x, ma.x, va.x)));
      o.h[1] = f2b(fmaxf(0.f, bnf(acc[i][1] + b1a.y, ga.y, ba.y, ma.y, va.y)));
      o.h[2] = f2b(fmaxf(0.f, bnf(acc[i][2] + b1a.z, ga.z, ba.z, ma.z, va.z)));
      o.h[3] = f2b(fmaxf(0.f, bnf(acc[i][3] + b1a.w, ga.w, ba.w, ma.w, va.w)));
      o.h[4] = f2b(fmaxf(0.f, bnf(acc[i][4] + b1b.x, gb.x, bb.x, mb.x, vb.x)));
      o.h[5] = f2b(fmaxf(0.f, bnf(acc[i][5] + b1b.y, gb.y, bb.y, mb.y, vb.y)));
      o.h[6] = f2b(fmaxf(0.f, bnf(acc[i][6] + b1b.z, gb.z, bb.z, mb.z, vb.z)));
      o.h[7] = f2b(fmaxf(0.f, bnf(acc[i][7] + b1b.w, gb.w, bb.w, mb.w, vb.w)));
      ((uint4*)Ts)[(ty + 8 * i) * 33 + tx] = o.u;   // row stride 264 bf16 = 33 uint4
    }
  }
  __syncthreads();
  // GEMM2: 64x256 @ 256x128 -> acc2[8][4]; k-chunks of 32
  float acc2[8][4];
  #pragma unroll
  for (int i = 0; i < 8; ++i)
    #pragma unroll
    for (int j = 0; j < 4; ++j) acc2[i][j] = 0.f;
  for (int kc = 0; kc < 8; ++kc) {
    #pragma unroll
    for (int i = 0; i < 4; ++i) {
      int fl = tid + i * 256;
      int r = fl >> 5, c4 = fl & 31;
      *(float4*)&Bs[r * 132 + c4 * 4] = ((const float4*)W2)[(kc * 32 + r) * 32 + c4];
    }
    __syncthreads();
    #pragma unroll
    for (int k = 0; k < 32; ++k) {
      float4 b4 = *(const float4*)&Bs[k * 132 + tx * 4];
      #pragma unroll
      for (int i = 0; i < 8; ++i) {
        float a = b2f(Ts[(ty + 8 * i) * 264 + kc * 32 + k]);
        acc2[i][0] += a * b4.x; acc2[i][1] += a * b4.y;
        acc2[i][2] += a * b4.z; acc2[i][3] += a * b4.w;
      }
    }
    __syncthreads();
  }
  // epilogue
  {
    float4 bv = *(const float4*)&b2[tx * 4];
    float4 g  = *(const float4*)&bnp[tx * 4];
    float4 bb = *(const float4*)&bnp[128 + tx * 4];
    float4 m  = *(const float4*)&bnp[256 + tx * 4];
    float4 vv = *(const float4*)&bnp[384 + tx * 4];
    #pragma unroll
    for (int i = 0; i < 8; ++i) {
      int row = r0 + ty + 8 * i;
      if (row < Nn) {
        float4 o;
        o.x = bnf(acc2[i][0] + bv.x, g.x, bb.x, m.x, vv.x);
        o.y = bnf(acc2[i][1] + bv.y, g.y, bb.y, m.y, vv.y);
        o.z = bnf(acc2[i][2] + bv.z, g.z, bb.z, m.z, vv.z);
        o.w = bnf(acc2[i][3] + bv.w, g.w, bb.w, m.w, vv.w);
        if (is_last) {
          ((float4*)out_f)[row * 32 + tx] = o;
        } else {
          U4 ob;
          ob.h[0] = f2b(fmaxf(0.f, o.x)); ob.h[1] = f2b(fmaxf(0.f, o.y));
          ob.h[2] = f2b(fmaxf(0.f, o.z)); ob.h[3] = f2b(fmaxf(0.f, o.w));
          ((ushort4*)out_b)[row * 32 + tx] = ob.u;
        }
      }
    }
  }
}

// -------- vt = segment_sum(h_in, batch) --------
__global__ void k_vt_sum(const bf16* __restrict__ h_in, const int* __restrict__ batch,
                         float* __restrict__ vt) {
  int d = threadIdx.x;  // 128 threads
  int chunk = (Nn + gridDim.x - 1) / gridDim.x;
  int r0 = blockIdx.x * chunk;
  int r1 = min(r0 + chunk, Nn);
  if (r0 >= r1) return;
  float acc = 0.f;
  int cur = batch[r0];
  for (int r = r0; r < r1; ++r) {
    int g = batch[r];
    if (g != cur) { atomicAdd(&vt[cur * Dd + d], acc); acc = 0.f; cur = g; }
    acc += b2f(h_in[r * Dd + d]);
  }
  atomicAdd(&vt[cur * Dd + d], acc);
}

// -------- virtual-node MLP (tiny) --------
__global__ __launch_bounds__(256) void k_vn_mlp(
    float* __restrict__ vn, const float* __restrict__ vt,
    const float* __restrict__ W1, const float* __restrict__ b1, const float* __restrict__ bn1,
    const float* __restrict__ W2, const float* __restrict__ b2, const float* __restrict__ bn2) {
  __shared__ float row[128];
  __shared__ float trow[256];
  int g = blockIdx.x;
  int tid = threadIdx.x;
  if (tid < 128) row[tid] = vt[g * Dd + tid] + vn[g * Dd + tid];
  __syncthreads();
  float acc = 0.f;
  for (int k = 0; k < 128; ++k) acc += row[k] * W1[k * 256 + tid];
  acc += b1[tid];
  trow[tid] = fmaxf(0.f, bnf(acc, bn1[tid], bn1[256 + tid], bn1[512 + tid], bn1[768 + tid]));
  __syncthreads();
  if (tid < 128) {
    float acc2 = 0.f;
    for (int k = 0; k < 256; ++k) acc2 += trow[k] * W2[k * Dd + tid];
    acc2 += b2[tid];
    vn[g * Dd + tid] = fmaxf(0.f, bnf(acc2, bn2[tid], bn2[128 + tid], bn2[256 + tid], bn2[384 + tid]));
  }
}

extern "C" void kernel_launch(void* const* d_in, const int* in_sizes, int n_in,
                              void* d_out, int out_size, void* d_ws, size_t ws_size,
                              hipStream_t stream) {
  const int*   x_node    = (const int*)  d_in[0];
  const int*   edge_idx  = (const int*)  d_in[1];
  const float* edge_attr = (const float*)d_in[2];
  const int*   batch     = (const int*)  d_in[3];
  const int*   pos_index = (const int*)  d_in[4];
  const float* pos_enc   = (const float*)d_in[5];
  const int*   pos_batch = (const int*)  d_in[6];
  const float* node_emb  = (const float*)d_in[7];
  const float* z_init    = (const float*)d_in[8];
  const float* ze_bn1    = (const float*)d_in[9];
  const float* ze_W      = (const float*)d_in[10];
  const float* ze_b      = (const float*)d_in[11];
  const float* ze_bn2    = (const float*)d_in[12];
  const float* vn_emb    = (const float*)d_in[13];
  const float* conv_We   = (const float*)d_in[14];
  const float* conv_be   = (const float*)d_in[15];
  const float* conv_Wp   = (const float*)d_in[16];
  const float* conv_bp   = (const float*)d_in[17];
  const float* conv_W1   = (const float*)d_in[18];
  const float* conv_b1   = (const float*)d_in[19];
  const float* conv_bn   = (const float*)d_in[20];
  const float* conv_W2   = (const float*)d_in[21];
  const float* conv_b2   = (const float*)d_in[22];
  const float* conv_eps  = (const float*)d_in[23];
  const float* layer_bn  = (const float*)d_in[24];
  const float* vn_W1     = (const float*)d_in[25];
  const float* vn_b1     = (const float*)d_in[26];
  const float* vn_bn1    = (const float*)d_in[27];
  const float* vn_W2     = (const float*)d_in[28];
  const float* vn_b2     = (const float*)d_in[29];
  const float* vn_bn2    = (const float*)d_in[30];

  // workspace (~79.4 MB) — same layout that ran OK in R3
  char* wb = (char*)d_ws;
  bf16*  h_in   = (bf16*)(wb);                      // N*128 bf16  = 25,600,000 B
  float* agg    = (float*)(wb + 25600000);          // N*128 f32   = 51,200,000 B
  float* vn     = (float*)(wb + 76800000);          // G*128 f32
  float* vt     = (float*)(wb + 76865536);          // G*128 f32
  int*   estart = (int*)  (wb + 76931072);          // (E+1) int

  const int* src = edge_idx;
  const int* dst = edge_idx + Ee;

  k_estart<<<(Ee + 256) / 256, 256, 0, stream>>>(pos_batch, estart);
  k_init_vn<<<(Gg * 128 + 255) / 256, 256, 0, stream>>>(vn_emb, vn);

  int hblocks = (Nn * 16 + 255) / 256;
  int mblocks = (Nn + 63) / 64;
  for (int l = 0; l < Ll; ++l) {
    if (l == 0) k_hin0<<<hblocks, 256, 0, stream>>>(x_node, node_emb, vn, batch, h_in);
    else        k_hin <<<hblocks, 256, 0, stream>>>(vn, batch, h_in);
    hipMemsetAsync(agg, 0, (size_t)Nn * 128 * 4, stream);
    k_edge_fused<<<Ee / 64, 256, 0, stream>>>(estart, pos_index, pos_enc, z_init,
        ze_bn1, ze_W, ze_b, ze_bn2,
        edge_attr, src, dst, h_in,
        conv_Wp + (size_t)l * 128 * 128, conv_We + (size_t)l * 7 * 128,
        conv_be + l * 128, conv_bp + l * 128, agg);
    if (l < Ll - 1) {
      hipMemsetAsync(vt, 0, (size_t)Gg * 128 * 4, stream);
      k_vt_sum<<<1024, 128, 0, stream>>>(h_in, batch, vt);
      k_vn_mlp<<<Gg, 256, 0, stream>>>(vn, vt,
          vn_W1 + (size_t)l * 128 * 256, vn_b1 + l * 256, vn_bn1 + (size_t)l * 4 * 256,
          vn_W2 + (size_t)l * 256 * 128, vn_b2 + l * 128, vn_bn2 + (size_t)l * 4 * 128);
    }
    k_mlp_fused<<<mblocks, 256, 0, stream>>>(h_in, agg, conv_eps, l,
        conv_W1 + (size_t)l * 128 * 256, conv_b1 + l * 256, conv_bn + (size_t)l * 4 * 256,
        conv_W2 + (size_t)l * 256 * 128, conv_b2 + l * 128, layer_bn + (size_t)l * 4 * 128,
        (l == Ll - 1) ? 1 : 0, h_in, (float*)d_out);
  }
}

// Round 5
// 2451.720 us; speedup vs baseline: 2.2837x; 2.2837x over previous
//
#include <hip/hip_runtime.h>
#include <hip/hip_bf16.h>

typedef __hip_bfloat16 bf16;
typedef __attribute__((ext_vector_type(8))) short short8;
typedef __attribute__((ext_vector_type(4))) float floatx4;

constexpr int Nn = 100000;   // nodes
constexpr int Ee = 640000;   // edges
constexpr int Pp = 640000;   // pos entries
constexpr int Gg = 128;      // graphs
constexpr int Ll = 3;        // layers
#define Dd 128
#define BN_EPS 1e-5f

__device__ __forceinline__ float b2f(bf16 x) { return __bfloat162float(x); }
__device__ __forceinline__ bf16 f2b(float x) { return __float2bfloat16(x); }

union U8 { uint4 u; bf16 h[8]; };
union U4 { ushort4 u; bf16 h[4]; };

__device__ __forceinline__ float bnf(float x, float g, float b, float m, float v) {
  return (x - m) * (1.0f / sqrtf(v + BN_EPS)) * g + b;
}

// -------- estart[e] = lower_bound(pos_batch, e), e in [0, E] --------
__global__ void k_estart(const int* __restrict__ pos_batch, int* __restrict__ estart) {
  int e = blockIdx.x * blockDim.x + threadIdx.x;
  if (e > Ee) return;
  int lo = 0, hi = Pp;
  while (lo < hi) { int mid = (lo + hi) >> 1; if (pos_batch[mid] < e) lo = mid + 1; else hi = mid; }
  estart[e] = lo;
}

// -------- pre-transpose weights to bf16 [n][k] for MFMA B-fragments --------
__global__ void k_prep(const float* __restrict__ zeW, const float* __restrict__ Wp,
                       bf16* __restrict__ zeWt, bf16* __restrict__ WpT) {
  int gid = blockIdx.x * blockDim.x + threadIdx.x;   // over 128*128
  if (gid >= 16384) return;
  int n = gid >> 7, k = gid & 127;
  zeWt[n * 128 + k] = f2b(zeW[k * 128 + n]);
  #pragma unroll
  for (int l = 0; l < 3; ++l)
    WpT[l * 16384 + n * 128 + k] = f2b(Wp[l * 16384 + k * 128 + n]);
}

__global__ void k_init_vn(const float* __restrict__ vn_emb, float* __restrict__ vn) {
  int gid = blockIdx.x * blockDim.x + threadIdx.x;
  if (gid >= Gg * 128) return;
  vn[gid] = vn_emb[gid & 127];
}

// -------- h_in = node_emb[x_node] + vn[batch]  (layer 0); bf16 store --------
__global__ void k_hin0(const int* __restrict__ x_node, const float* __restrict__ node_emb,
                       const float* __restrict__ vn, const int* __restrict__ batch,
                       bf16* __restrict__ h_in) {
  int gid = blockIdx.x * blockDim.x + threadIdx.x;
  if (gid >= Nn * 16) return;
  int n = gid >> 4, c = gid & 15;
  int x = x_node[n], b = batch[n];
  float4 a0 = ((const float4*)node_emb)[x * 32 + c * 2];
  float4 a1 = ((const float4*)node_emb)[x * 32 + c * 2 + 1];
  float4 v0 = ((const float4*)vn)[b * 32 + c * 2];
  float4 v1 = ((const float4*)vn)[b * 32 + c * 2 + 1];
  U8 o;
  o.h[0] = f2b(a0.x + v0.x); o.h[1] = f2b(a0.y + v0.y);
  o.h[2] = f2b(a0.z + v0.z); o.h[3] = f2b(a0.w + v0.w);
  o.h[4] = f2b(a1.x + v1.x); o.h[5] = f2b(a1.y + v1.y);
  o.h[6] = f2b(a1.z + v1.z); o.h[7] = f2b(a1.w + v1.w);
  ((uint4*)h_in)[gid] = o.u;
}

// -------- h_in += vn[batch]  (layers 1..) in-place --------
__global__ void k_hin(const float* __restrict__ vn, const int* __restrict__ batch,
                      bf16* __restrict__ h_in) {
  int gid = blockIdx.x * blockDim.x + threadIdx.x;
  if (gid >= Nn * 16) return;
  int n = gid >> 4, c = gid & 15;
  U8 a; a.u = ((const uint4*)h_in)[gid];
  int b = batch[n];
  float4 v0 = ((const float4*)vn)[b * 32 + c * 2];
  float4 v1 = ((const float4*)vn)[b * 32 + c * 2 + 1];
  U8 o;
  o.h[0] = f2b(b2f(a.h[0]) + v0.x); o.h[1] = f2b(b2f(a.h[1]) + v0.y);
  o.h[2] = f2b(b2f(a.h[2]) + v0.z); o.h[3] = f2b(b2f(a.h[3]) + v0.w);
  o.h[4] = f2b(b2f(a.h[4]) + v1.x); o.h[5] = f2b(b2f(a.h[5]) + v1.y);
  o.h[6] = f2b(b2f(a.h[6]) + v1.z); o.h[7] = f2b(b2f(a.h[7]) + v1.w);
  ((uint4*)h_in)[gid] = o.u;
}

// -------- fused edge kernel, MFMA version --------
// zpool = segsum(z_init[pos_index]*pos_enc) -> bn1/relu -> bf16 Az
// T = Az @ zeWt (MFMA), z = relu(bn2(T + ze_b)) -> Az
// U = eattr@We (VALU init) + Az @ WpT (MFMA)
// msg = relu(h_in[src] + U + be + bp); agg[dst] += msg (f32 atomics)
__global__ __launch_bounds__(256) void k_edge_fused(
    const int* __restrict__ estart, const int* __restrict__ pos_index,
    const float* __restrict__ pos_enc, const float* __restrict__ z_init,
    const float* __restrict__ ze_bn1, const bf16* __restrict__ zeWt,
    const float* __restrict__ ze_b, const float* __restrict__ ze_bn2,
    const float* __restrict__ eattr, const int* __restrict__ src,
    const int* __restrict__ dst, const bf16* __restrict__ h_in,
    const bf16* __restrict__ WpT, const float* __restrict__ We,
    const float* __restrict__ be, const float* __restrict__ bp,
    float* __restrict__ agg) {
  __shared__ bf16 Az[64][136];          // A tile (zpool, then z), padded
  __shared__ bf16 Bt[128][136];         // B^T tile (zeWt, then WpT)
  __shared__ float Ea[64][8];           // eattr tile
  __shared__ float WeS[7][128];         // We
  __shared__ float zeb_s[128], g2s[128], b2s[128], m2s[128], v2s[128], biasEP[128];
  int tid = threadIdx.x;
  int lane = tid & 63, wv = tid >> 6;   // wave id 0..3
  int q = lane >> 4, ln = lane & 15;    // quad, lane-in-16
  int e0 = blockIdx.x * 64;

  // ---- phase 1: stage everything ----
  if (tid < 224) {                       // We: 7x128 f32
    int r = tid >> 5, c4 = tid & 31;
    *(float4*)&WeS[r][c4 * 4] = ((const float4*)We)[tid];
  }
  if (tid < 128) {
    zeb_s[tid] = ze_b[tid];
    g2s[tid] = ze_bn2[tid]; b2s[tid] = ze_bn2[128 + tid];
    m2s[tid] = ze_bn2[256 + tid]; v2s[tid] = ze_bn2[384 + tid];
    biasEP[tid] = be[tid] + bp[tid];
  }
  for (int idx = tid; idx < 448; idx += 256) {
    int r = idx / 7, c = idx % 7;
    Ea[r][c] = eattr[(e0 + r) * 7 + c];
  }
  #pragma unroll
  for (int i = 0; i < 8; ++i) {          // Bt <- zeWt (32 KB)
    int fl = tid + i * 256;
    int n = fl >> 4, kv = fl & 15;
    *(uint4*)&Bt[n][kv * 8] = ((const uint4*)zeWt)[fl];
  }
  {  // zpool gather: thread -> edge r = tid>>2, 32-col chunk cc = tid&3
    int r = tid >> 2, cc = tid & 3;
    int e = e0 + r;
    int ps = estart[e], pe = estart[e + 1];
    float acc[32];
    #pragma unroll
    for (int j = 0; j < 32; ++j) acc[j] = 0.f;
    for (int p = ps; p < pe; ++p) {
      int idx = pos_index[p];
      float w = pos_enc[p];
      #pragma unroll
      for (int qq = 0; qq < 8; ++qq) {
        float4 z4 = ((const float4*)z_init)[idx * 32 + cc * 8 + qq];
        acc[qq * 4 + 0] = fmaf(w, z4.x, acc[qq * 4 + 0]);
        acc[qq * 4 + 1] = fmaf(w, z4.y, acc[qq * 4 + 1]);
        acc[qq * 4 + 2] = fmaf(w, z4.z, acc[qq * 4 + 2]);
        acc[qq * 4 + 3] = fmaf(w, z4.w, acc[qq * 4 + 3]);
      }
    }
    #pragma unroll
    for (int qq = 0; qq < 4; ++qq) {     // bn1+relu, pack 8 bf16 -> Az
      U8 o;
      #pragma unroll
      for (int jj = 0; jj < 2; ++jj) {
        int col = cc * 32 + qq * 8 + jj * 4;
        float4 g = *(const float4*)&ze_bn1[col];
        float4 b = *(const float4*)&ze_bn1[128 + col];
        float4 m = *(const float4*)&ze_bn1[256 + col];
        float4 v = *(const float4*)&ze_bn1[384 + col];
        o.h[jj * 4 + 0] = f2b(fmaxf(0.f, bnf(acc[qq * 8 + jj * 4 + 0], g.x, b.x, m.x, v.x)));
        o.h[jj * 4 + 1] = f2b(fmaxf(0.f, bnf(acc[qq * 8 + jj * 4 + 1], g.y, b.y, m.y, v.y)));
        o.h[jj * 4 + 2] = f2b(fmaxf(0.f, bnf(acc[qq * 8 + jj * 4 + 2], g.z, b.z, m.z, v.z)));
        o.h[jj * 4 + 3] = f2b(fmaxf(0.f, bnf(acc[qq * 8 + jj * 4 + 3], g.w, b.w, m.w, v.w)));
      }
      *(uint4*)&Az[r][cc * 32 + qq * 8] = o.u;
    }
  }
  __syncthreads();

  // ---- GEMM1: acc1 = Az @ zeWt  (each wave: rows 16wv..16wv+15, all 128 cols)
  floatx4 acc1[8] = {};
  #pragma unroll
  for (int kc = 0; kc < 4; ++kc) {
    short8 af = *(const short8*)&Az[16 * wv + ln][kc * 32 + q * 8];
    #pragma unroll
    for (int t = 0; t < 8; ++t) {
      short8 bfr = *(const short8*)&Bt[t * 16 + ln][kc * 32 + q * 8];
      acc1[t] = __builtin_amdgcn_mfma_f32_16x16x32_bf16(af, bfr, acc1[t], 0, 0, 0);
    }
  }
  // acc2 init = Ea @ We in C-layout (col=ln within tile t, row=q*4+r)
  floatx4 acc2[8];
  #pragma unroll
  for (int t = 0; t < 8; ++t) {
    int c = t * 16 + ln;
    float wk[7];
    #pragma unroll
    for (int k = 0; k < 7; ++k) wk[k] = WeS[k][c];
    #pragma unroll
    for (int r = 0; r < 4; ++r) {
      int row = 16 * wv + q * 4 + r;
      float s = 0.f;
      #pragma unroll
      for (int k = 0; k < 7; ++k) s = fmaf(Ea[row][k], wk[k], s);
      acc2[t][r] = s;
    }
  }
  // z = relu(bn2(acc1 + ze_b)) -> own rows of Az (intra-wave only; no barrier needed)
  #pragma unroll
  for (int t = 0; t < 8; ++t) {
    int c = t * 16 + ln;
    float zb = zeb_s[c], gg = g2s[c], bb = b2s[c], mm = m2s[c], vv = v2s[c];
    #pragma unroll
    for (int r = 0; r < 4; ++r) {
      int row = 16 * wv + q * 4 + r;
      Az[row][c] = f2b(fmaxf(0.f, bnf(acc1[t][r] + zb, gg, bb, mm, vv)));
    }
  }
  __syncthreads();   // all waves done reading Bt(zeWt)
  #pragma unroll
  for (int i = 0; i < 8; ++i) {          // Bt <- WpT
    int fl = tid + i * 256;
    int n = fl >> 4, kv = fl & 15;
    *(uint4*)&Bt[n][kv * 8] = ((const uint4*)WpT)[fl];
  }
  __syncthreads();

  // ---- GEMM2: acc2 += Az(z) @ WpT
  #pragma unroll
  for (int kc = 0; kc < 4; ++kc) {
    short8 af = *(const short8*)&Az[16 * wv + ln][kc * 32 + q * 8];
    #pragma unroll
    for (int t = 0; t < 8; ++t) {
      short8 bfr = *(const short8*)&Bt[t * 16 + ln][kc * 32 + q * 8];
      acc2[t] = __builtin_amdgcn_mfma_f32_16x16x32_bf16(af, bfr, acc2[t], 0, 0, 0);
    }
  }
  // ---- epilogue: gather h_in[src], relu, atomic scatter to agg[dst]
  #pragma unroll
  for (int r = 0; r < 4; ++r) {
    int e = e0 + 16 * wv + q * 4 + r;
    int s = src[e], d2 = dst[e];
    #pragma unroll
    for (int t = 0; t < 8; ++t) {
      int c = t * 16 + ln;
      float val = acc2[t][r] + biasEP[c] + b2f(h_in[(size_t)s * Dd + c]);
      val = fmaxf(0.f, val);
      atomicAdd(&agg[(size_t)d2 * Dd + c], val);
    }
  }
}

// -------- fused node MLP: x=(1+eps)*h_in+agg; t=relu(bn(x@W1+b1)); out=bn2(t@W2+b2)[,relu]
__global__ __launch_bounds__(256) void k_mlp_fused(
    const bf16* __restrict__ h_in, const float* __restrict__ agg,
    const float* __restrict__ eps_arr, int l,
    const float* __restrict__ W1, const float* __restrict__ b1, const float* __restrict__ bn,
    const float* __restrict__ W2, const float* __restrict__ b2, const float* __restrict__ bnp,
    int is_last, bf16* __restrict__ out_b, float* __restrict__ out_f) {
  __shared__ alignas(16) float As[64 * 132];   // phase2: reused as bf16 Ts[64][264]
  __shared__ alignas(16) float Bs[4224];       // phase1: [16][264]; phase2: [32][132]
  bf16* Ts = (bf16*)As;
  int tid = threadIdx.x;
  int tx = tid & 31, ty = tid >> 5;
  int r0 = blockIdx.x * 64;
  float epsv = 1.0f + eps_arr[l];
  #pragma unroll
  for (int i = 0; i < 4; ++i) {
    int fl = tid + i * 256;
    int r = fl >> 4, c = fl & 15;
    int row = r0 + r;
    float v[8] = {0.f, 0.f, 0.f, 0.f, 0.f, 0.f, 0.f, 0.f};
    if (row < Nn) {
      U8 hh; hh.u = ((const uint4*)h_in)[row * 16 + c];
      float4 g0 = ((const float4*)agg)[row * 32 + c * 2];
      float4 g1 = ((const float4*)agg)[row * 32 + c * 2 + 1];
      v[0] = epsv * b2f(hh.h[0]) + g0.x; v[1] = epsv * b2f(hh.h[1]) + g0.y;
      v[2] = epsv * b2f(hh.h[2]) + g0.z; v[3] = epsv * b2f(hh.h[3]) + g0.w;
      v[4] = epsv * b2f(hh.h[4]) + g1.x; v[5] = epsv * b2f(hh.h[5]) + g1.y;
      v[6] = epsv * b2f(hh.h[6]) + g1.z; v[7] = epsv * b2f(hh.h[7]) + g1.w;
    }
    #pragma unroll
    for (int j = 0; j < 8; ++j) As[r * 132 + c * 8 + j] = v[j];
  }
  __syncthreads();
  float acc[8][8];
  #pragma unroll
  for (int i = 0; i < 8; ++i)
    #pragma unroll
    for (int j = 0; j < 8; ++j) acc[i][j] = 0.f;
  for (int kc = 0; kc < 8; ++kc) {
    #pragma unroll
    for (int i = 0; i < 4; ++i) {
      int fl = tid + i * 256;
      int r = fl >> 6, c4 = fl & 63;
      *(float4*)&Bs[r * 264 + c4 * 4] = ((const float4*)W1)[(kc * 16 + r) * 64 + c4];
    }
    __syncthreads();
    #pragma unroll
    for (int k = 0; k < 16; ++k) {
      float4 bA = *(const float4*)&Bs[k * 264 + tx * 8];
      float4 bB = *(const float4*)&Bs[k * 264 + tx * 8 + 4];
      #pragma unroll
      for (int i = 0; i < 8; ++i) {
        float a = As[(ty + 8 * i) * 132 + kc * 16 + k];
        acc[i][0] += a * bA.x; acc[i][1] += a * bA.y;
        acc[i][2] += a * bA.z; acc[i][3] += a * bA.w;
        acc[i][4] += a * bB.x; acc[i][5] += a * bB.y;
        acc[i][6] += a * bB.z; acc[i][7] += a * bB.w;
      }
    }
    __syncthreads();
  }
  {
    float4 b1a = *(const float4*)&b1[tx * 8];       float4 b1b = *(const float4*)&b1[tx * 8 + 4];
    float4 ga  = *(const float4*)&bn[tx * 8];       float4 gb  = *(const float4*)&bn[tx * 8 + 4];
    float4 ba  = *(const float4*)&bn[256 + tx * 8]; float4 bb  = *(const float4*)&bn[256 + tx * 8 + 4];
    float4 ma  = *(const float4*)&bn[512 + tx * 8]; float4 mb  = *(const float4*)&bn[512 + tx * 8 + 4];
    float4 va  = *(const float4*)&bn[768 + tx * 8]; float4 vb  = *(const float4*)&bn[768 + tx * 8 + 4];
    #pragma unroll
    for (int i = 0; i < 8; ++i) {
      U8 o;
      o.h[0] = f2b(fmaxf(0.f, bnf(acc[i][0] + b1a.x, ga.x, ba.x, ma.x, va.x)));
      o.h[1] = f2b(fmaxf(0.f, bnf(acc[i][1] + b1a.y, ga.y, ba.y, ma.y, va.y)));
      o.h[2] = f2b(fmaxf(0.f, bnf(acc[i][2] + b1a.z, ga.z, ba.z, ma.z, va.z)));
      o.h[3] = f2b(fmaxf(0.f, bnf(acc[i][3] + b1a.w, ga.w, ba.w, ma.w, va.w)));
      o.h[4] = f2b(fmaxf(0.f, bnf(acc[i][4] + b1b.x, gb.x, bb.x, mb.x, vb.x)));
      o.h[5] = f2b(fmaxf(0.f, bnf(acc[i][5] + b1b.y, gb.y, bb.y, mb.y, vb.y)));
      o.h[6] = f2b(fmaxf(0.f, bnf(acc[i][6] + b1b.z, gb.z, bb.z, mb.z, vb.z)));
      o.h[7] = f2b(fmaxf(0.f, bnf(acc[i][7] + b1b.w, gb.w, bb.w, mb.w, vb.w)));
      ((uint4*)Ts)[(ty + 8 * i) * 33 + tx] = o.u;
    }
  }
  __syncthreads();
  float acc2[8][4];
  #pragma unroll
  for (int i = 0; i < 8; ++i)
    #pragma unroll
    for (int j = 0; j < 4; ++j) acc2[i][j] = 0.f;
  for (int kc = 0; kc < 8; ++kc) {
    #pragma unroll
    for (int i = 0; i < 4; ++i) {
      int fl = tid + i * 256;
      int r = fl >> 5, c4 = fl & 31;
      *(float4*)&Bs[r * 132 + c4 * 4] = ((const float4*)W2)[(kc * 32 + r) * 32 + c4];
    }
    __syncthreads();
    #pragma unroll
    for (int k = 0; k < 32; ++k) {
      float4 b4 = *(const float4*)&Bs[k * 132 + tx * 4];
      #pragma unroll
      for (int i = 0; i < 8; ++i) {
        float a = b2f(Ts[(ty + 8 * i) * 264 + kc * 32 + k]);
        acc2[i][0] += a * b4.x; acc2[i][1] += a * b4.y;
        acc2[i][2] += a * b4.z; acc2[i][3] += a * b4.w;
      }
    }
    __syncthreads();
  }
  {
    float4 bv = *(const float4*)&b2[tx * 4];
    float4 g  = *(const float4*)&bnp[tx * 4];
    float4 bb = *(const float4*)&bnp[128 + tx * 4];
    float4 m  = *(const float4*)&bnp[256 + tx * 4];
    float4 vv = *(const float4*)&bnp[384 + tx * 4];
    #pragma unroll
    for (int i = 0; i < 8; ++i) {
      int row = r0 + ty + 8 * i;
      if (row < Nn) {
        float4 o;
        o.x = bnf(acc2[i][0] + bv.x, g.x, bb.x, m.x, vv.x);
        o.y = bnf(acc2[i][1] + bv.y, g.y, bb.y, m.y, vv.y);
        o.z = bnf(acc2[i][2] + bv.z, g.z, bb.z, m.z, vv.z);
        o.w = bnf(acc2[i][3] + bv.w, g.w, bb.w, m.w, vv.w);
        if (is_last) {
          ((float4*)out_f)[row * 32 + tx] = o;
        } else {
          U4 ob;
          ob.h[0] = f2b(fmaxf(0.f, o.x)); ob.h[1] = f2b(fmaxf(0.f, o.y));
          ob.h[2] = f2b(fmaxf(0.f, o.z)); ob.h[3] = f2b(fmaxf(0.f, o.w));
          ((ushort4*)out_b)[row * 32 + tx] = ob.u;
        }
      }
    }
  }
}

// -------- vt = segment_sum(h_in, batch) --------
__global__ void k_vt_sum(const bf16* __restrict__ h_in, const int* __restrict__ batch,
                         float* __restrict__ vt) {
  int d = threadIdx.x;
  int chunk = (Nn + gridDim.x - 1) / gridDim.x;
  int r0 = blockIdx.x * chunk;
  int r1 = min(r0 + chunk, Nn);
  if (r0 >= r1) return;
  float acc = 0.f;
  int cur = batch[r0];
  for (int r = r0; r < r1; ++r) {
    int g = batch[r];
    if (g != cur) { atomicAdd(&vt[cur * Dd + d], acc); acc = 0.f; cur = g; }
    acc += b2f(h_in[r * Dd + d]);
  }
  atomicAdd(&vt[cur * Dd + d], acc);
}

// -------- virtual-node MLP (tiny) --------
__global__ __launch_bounds__(256) void k_vn_mlp(
    float* __restrict__ vn, const float* __restrict__ vt,
    const float* __restrict__ W1, const float* __restrict__ b1, const float* __restrict__ bn1,
    const float* __restrict__ W2, const float* __restrict__ b2, const float* __restrict__ bn2) {
  __shared__ float row[128];
  __shared__ float trow[256];
  int g = blockIdx.x;
  int tid = threadIdx.x;
  if (tid < 128) row[tid] = vt[g * Dd + tid] + vn[g * Dd + tid];
  __syncthreads();
  float acc = 0.f;
  for (int k = 0; k < 128; ++k) acc += row[k] * W1[k * 256 + tid];
  acc += b1[tid];
  trow[tid] = fmaxf(0.f, bnf(acc, bn1[tid], bn1[256 + tid], bn1[512 + tid], bn1[768 + tid]));
  __syncthreads();
  if (tid < 128) {
    float acc2 = 0.f;
    for (int k = 0; k < 256; ++k) acc2 += trow[k] * W2[k * Dd + tid];
    acc2 += b2[tid];
    vn[g * Dd + tid] = fmaxf(0.f, bnf(acc2, bn2[tid], bn2[128 + tid], bn2[256 + tid], bn2[384 + tid]));
  }
}

extern "C" void kernel_launch(void* const* d_in, const int* in_sizes, int n_in,
                              void* d_out, int out_size, void* d_ws, size_t ws_size,
                              hipStream_t stream) {
  const int*   x_node    = (const int*)  d_in[0];
  const int*   edge_idx  = (const int*)  d_in[1];
  const float* edge_attr = (const float*)d_in[2];
  const int*   batch     = (const int*)  d_in[3];
  const int*   pos_index = (const int*)  d_in[4];
  const float* pos_enc   = (const float*)d_in[5];
  const int*   pos_batch = (const int*)  d_in[6];
  const float* node_emb  = (const float*)d_in[7];
  const float* z_init    = (const float*)d_in[8];
  const float* ze_bn1    = (const float*)d_in[9];
  const float* ze_W      = (const float*)d_in[10];
  const float* ze_b      = (const float*)d_in[11];
  const float* ze_bn2    = (const float*)d_in[12];
  const float* vn_emb    = (const float*)d_in[13];
  const float* conv_We   = (const float*)d_in[14];
  const float* conv_be   = (const float*)d_in[15];
  const float* conv_Wp   = (const float*)d_in[16];
  const float* conv_bp   = (const float*)d_in[17];
  const float* conv_W1   = (const float*)d_in[18];
  const float* conv_b1   = (const float*)d_in[19];
  const float* conv_bn   = (const float*)d_in[20];
  const float* conv_W2   = (const float*)d_in[21];
  const float* conv_b2   = (const float*)d_in[22];
  const float* conv_eps  = (const float*)d_in[23];
  const float* layer_bn  = (const float*)d_in[24];
  const float* vn_W1     = (const float*)d_in[25];
  const float* vn_b1     = (const float*)d_in[26];
  const float* vn_bn1    = (const float*)d_in[27];
  const float* vn_W2     = (const float*)d_in[28];
  const float* vn_b2     = (const float*)d_in[29];
  const float* vn_bn2    = (const float*)d_in[30];

  // workspace (~79.6 MB) — R4 layout + transposed weight tables
  char* wb = (char*)d_ws;
  bf16*  h_in   = (bf16*)(wb);                      // N*128 bf16
  float* agg    = (float*)(wb + 25600000);          // N*128 f32
  float* vn     = (float*)(wb + 76800000);          // G*128 f32
  float* vt     = (float*)(wb + 76865536);          // G*128 f32
  int*   estart = (int*)  (wb + 76931072);          // (E+1) int
  bf16*  zeWt   = (bf16*) (wb + 79491088);          // 128*128 bf16 = 32 KB
  bf16*  WpT    = (bf16*) (wb + 79523856);          // 3*128*128 bf16 = 96 KB

  const int* src = edge_idx;
  const int* dst = edge_idx + Ee;

  k_estart<<<(Ee + 256) / 256, 256, 0, stream>>>(pos_batch, estart);
  k_prep<<<64, 256, 0, stream>>>(ze_W, conv_Wp, zeWt, WpT);
  k_init_vn<<<(Gg * 128 + 255) / 256, 256, 0, stream>>>(vn_emb, vn);

  int hblocks = (Nn * 16 + 255) / 256;
  int mblocks = (Nn + 63) / 64;
  for (int l = 0; l < Ll; ++l) {
    if (l == 0) k_hin0<<<hblocks, 256, 0, stream>>>(x_node, node_emb, vn, batch, h_in);
    else        k_hin <<<hblocks, 256, 0, stream>>>(vn, batch, h_in);
    hipMemsetAsync(agg, 0, (size_t)Nn * 128 * 4, stream);
    k_edge_fused<<<Ee / 64, 256, 0, stream>>>(estart, pos_index, pos_enc, z_init,
        ze_bn1, zeWt, ze_b, ze_bn2,
        edge_attr, src, dst, h_in,
        WpT + (size_t)l * 128 * 128, conv_We + (size_t)l * 7 * 128,
        conv_be + l * 128, conv_bp + l * 128, agg);
    if (l < Ll - 1) {
      hipMemsetAsync(vt, 0, (size_t)Gg * 128 * 4, stream);
      k_vt_sum<<<1024, 128, 0, stream>>>(h_in, batch, vt);
      k_vn_mlp<<<Gg, 256, 0, stream>>>(vn, vt,
          vn_W1 + (size_t)l * 128 * 256, vn_b1 + l * 256, vn_bn1 + (size_t)l * 4 * 256,
          vn_W2 + (size_t)l * 256 * 128, vn_b2 + l * 128, vn_bn2 + (size_t)l * 4 * 128);
    }
    k_mlp_fused<<<mblocks, 256, 0, stream>>>(h_in, agg, conv_eps, l,
        conv_W1 + (size_t)l * 128 * 256, conv_b1 + l * 256, conv_bn + (size_t)l * 4 * 256,
        conv_W2 + (size_t)l * 256 * 128, conv_b2 + l * 128, layer_bn + (size_t)l * 4 * 128,
        (l == Ll - 1) ? 1 : 0, h_in, (float*)d_out);
  }
}

// Round 6
// 1983.110 us; speedup vs baseline: 2.8233x; 1.2363x over previous
//
#include <hip/hip_runtime.h>
#include <hip/hip_bf16.h>

typedef __hip_bfloat16 bf16;
typedef __attribute__((ext_vector_type(8))) short short8;
typedef __attribute__((ext_vector_type(4))) float floatx4;

constexpr int Nn = 100000;   // nodes
constexpr int Ee = 640000;   // edges
constexpr int Pp = 640000;   // pos entries
constexpr int Gg = 128;      // graphs
constexpr int Ll = 3;        // layers
#define Dd 128
#define BN_EPS 1e-5f

__device__ __forceinline__ float b2f(bf16 x) { return __bfloat162float(x); }
__device__ __forceinline__ bf16 f2b(float x) { return __float2bfloat16(x); }

union U8 { uint4 u; bf16 h[8]; };

__device__ __forceinline__ float bnf(float x, float g, float b, float m, float v) {
  return (x - m) * (1.0f / sqrtf(v + BN_EPS)) * g + b;
}

// -------- estart[e] = lower_bound(pos_batch, e) --------
__global__ void k_estart(const int* __restrict__ pos_batch, int* __restrict__ estart) {
  int e = blockIdx.x * blockDim.x + threadIdx.x;
  if (e > Ee) return;
  int lo = 0, hi = Pp;
  while (lo < hi) { int mid = (lo + hi) >> 1; if (pos_batch[mid] < e) lo = mid + 1; else hi = mid; }
  estart[e] = lo;
}

// -------- pre-swizzle weights into MFMA B-fragment order: [kc][t][lane][8] --------
// B-frag element: k = kc*32 + (lane>>4)*8 + j ; n = t*16 + (lane&15)
__global__ void k_prep(const float* __restrict__ zeW, const float* __restrict__ Wp,
                       const float* __restrict__ We, const float* __restrict__ be,
                       const float* __restrict__ bp,
                       const float* __restrict__ W1, const float* __restrict__ W2,
                       bf16* __restrict__ zeWsw, bf16* __restrict__ WpSw,
                       bf16* __restrict__ WeSw, bf16* __restrict__ W1sw,
                       bf16* __restrict__ W2sw) {
  int gid = blockIdx.x * blockDim.x + threadIdx.x;
  // zeWsw: 16384   [kc4][t8][lane][8]
  if (gid < 16384) {
    int i = gid;
    int j = i & 7, lane = (i >> 3) & 63, t = (i >> 9) & 7, kc = i >> 12;
    int k = kc * 32 + ((lane >> 4) * 8) + j, n = t * 16 + (lane & 15);
    zeWsw[i] = f2b(zeW[k * 128 + n]);
  }
  // WpSw: 3 x 16384
  if (gid < 49152) {
    int l = gid / 16384, i = gid % 16384;
    int j = i & 7, lane = (i >> 3) & 63, t = (i >> 9) & 7, kc = i >> 12;
    int k = kc * 32 + ((lane >> 4) * 8) + j, n = t * 16 + (lane & 15);
    WpSw[gid] = f2b(Wp[l * 16384 + k * 128 + n]);
  }
  // WeSw: 3 x 4096  [t8][lane][8], kc=0, K padded to 32; k==7 = be+bp (bias col)
  if (gid < 12288) {
    int l = gid / 4096, i = gid % 4096;
    int j = i & 7, lane = (i >> 3) & 63, t = i >> 9;
    int k = ((lane >> 4) * 8) + j, n = t * 16 + (lane & 15);
    float v = 0.f;
    if (k < 7) v = We[l * 896 + k * 128 + n];
    else if (k == 7) v = be[l * 128 + n] + bp[l * 128 + n];
    WeSw[gid] = f2b(v);
  }
  // W1sw: 3 x 32768  [kc4][t16][lane][8]  (W1: 128x256)
  if (gid < 98304) {
    int l = gid / 32768, i = gid % 32768;
    int j = i & 7, lane = (i >> 3) & 63, t = (i >> 9) & 15, kc = i >> 13;
    int k = kc * 32 + ((lane >> 4) * 8) + j, n = t * 16 + (lane & 15);
    W1sw[gid] = f2b(W1[l * 32768 + k * 256 + n]);
  }
  // W2sw: 3 x 32768  [kc8][t8][lane][8]  (W2: 256x128)
  if (gid < 98304) {
    int l = gid / 32768, i = gid % 32768;
    int j = i & 7, lane = (i >> 3) & 63, t = (i >> 9) & 7, kc = i >> 12;
    int k = kc * 32 + ((lane >> 4) * 8) + j, n = t * 16 + (lane & 15);
    W2sw[gid] = f2b(W2[l * 32768 + k * 128 + n]);
  }
}

__global__ void k_init_vn(const float* __restrict__ vn_emb, float* __restrict__ vn) {
  int gid = blockIdx.x * blockDim.x + threadIdx.x;
  if (gid >= Gg * 128) return;
  vn[gid] = vn_emb[gid & 127];
}

// -------- h_in = node_emb[x_node] + vn[batch]  (layer 0) --------
__global__ void k_hin0(const int* __restrict__ x_node, const float* __restrict__ node_emb,
                       const float* __restrict__ vn, const int* __restrict__ batch,
                       bf16* __restrict__ h_in) {
  int gid = blockIdx.x * blockDim.x + threadIdx.x;
  if (gid >= Nn * 16) return;
  int n = gid >> 4, c = gid & 15;
  int x = x_node[n], b = batch[n];
  float4 a0 = ((const float4*)node_emb)[x * 32 + c * 2];
  float4 a1 = ((const float4*)node_emb)[x * 32 + c * 2 + 1];
  float4 v0 = ((const float4*)vn)[b * 32 + c * 2];
  float4 v1 = ((const float4*)vn)[b * 32 + c * 2 + 1];
  U8 o;
  o.h[0] = f2b(a0.x + v0.x); o.h[1] = f2b(a0.y + v0.y);
  o.h[2] = f2b(a0.z + v0.z); o.h[3] = f2b(a0.w + v0.w);
  o.h[4] = f2b(a1.x + v1.x); o.h[5] = f2b(a1.y + v1.y);
  o.h[6] = f2b(a1.z + v1.z); o.h[7] = f2b(a1.w + v1.w);
  ((uint4*)h_in)[gid] = o.u;
}

// -------- h_in += vn[batch]  (layers 1..) --------
__global__ void k_hin(const float* __restrict__ vn, const int* __restrict__ batch,
                      bf16* __restrict__ h_in) {
  int gid = blockIdx.x * blockDim.x + threadIdx.x;
  if (gid >= Nn * 16) return;
  int n = gid >> 4, c = gid & 15;
  U8 a; a.u = ((const uint4*)h_in)[gid];
  int b = batch[n];
  float4 v0 = ((const float4*)vn)[b * 32 + c * 2];
  float4 v1 = ((const float4*)vn)[b * 32 + c * 2 + 1];
  U8 o;
  o.h[0] = f2b(b2f(a.h[0]) + v0.x); o.h[1] = f2b(b2f(a.h[1]) + v0.y);
  o.h[2] = f2b(b2f(a.h[2]) + v0.z); o.h[3] = f2b(b2f(a.h[3]) + v0.w);
  o.h[4] = f2b(b2f(a.h[4]) + v1.x); o.h[5] = f2b(b2f(a.h[5]) + v1.y);
  o.h[6] = f2b(b2f(a.h[6]) + v1.z); o.h[7] = f2b(b2f(a.h[7]) + v1.w);
  ((uint4*)h_in)[gid] = o.u;
}

// -------- fused edge kernel, barrier-free MFMA version --------
__global__ __launch_bounds__(256, 4) void k_edge_fused(
    const int* __restrict__ estart, const int* __restrict__ pos_index,
    const float* __restrict__ pos_enc, const float* __restrict__ z_init,
    const float* __restrict__ ze_bn1, const bf16* __restrict__ zeWsw,
    const float* __restrict__ ze_b, const float* __restrict__ ze_bn2,
    const float* __restrict__ eattr, const int* __restrict__ src,
    const int* __restrict__ dst, const bf16* __restrict__ h_in,
    const bf16* __restrict__ WpSw, const bf16* __restrict__ WeSw,
    float* __restrict__ agg) {
  __shared__ bf16 Az[64][136];   // wave-exclusive rows 16wv..16wv+15
  __shared__ bf16 EaB[64][40];   // eattr, K padded to 32 (k7 = 1.0 bias col)
  int tid = threadIdx.x;
  int lane = tid & 63, wv = tid >> 6;
  int q = lane >> 4, ln = lane & 15;
  int e0 = blockIdx.x * 64;

  // ---- stage EaB (wave-exclusive): lane -> row=lane>>2, cols (lane&3)*8..+7
  {
    int r = lane >> 2, c0 = (lane & 3) * 8;
    int e = e0 + 16 * wv + r;
    U8 o;
    #pragma unroll
    for (int j = 0; j < 8; ++j) {
      int c = c0 + j;
      float v = 0.f;
      if (c < 7) v = eattr[(size_t)e * 7 + c];
      else if (c == 7) v = 1.0f;
      o.h[j] = f2b(v);
    }
    *(uint4*)&EaB[16 * wv + r][c0] = o.u;
  }
  // ---- zpool gather + bn1/relu -> Az (wave-exclusive)
  {
    int r = lane >> 2, cc = lane & 3;
    int e = e0 + 16 * wv + r;
    int ps = estart[e], pe = estart[e + 1];
    float acc[32];
    #pragma unroll
    for (int j = 0; j < 32; ++j) acc[j] = 0.f;
    for (int p = ps; p < pe; ++p) {
      int idx = pos_index[p];
      float w = pos_enc[p];
      #pragma unroll
      for (int qq = 0; qq < 8; ++qq) {
        float4 z4 = ((const float4*)z_init)[idx * 32 + cc * 8 + qq];
        acc[qq * 4 + 0] = fmaf(w, z4.x, acc[qq * 4 + 0]);
        acc[qq * 4 + 1] = fmaf(w, z4.y, acc[qq * 4 + 1]);
        acc[qq * 4 + 2] = fmaf(w, z4.z, acc[qq * 4 + 2]);
        acc[qq * 4 + 3] = fmaf(w, z4.w, acc[qq * 4 + 3]);
      }
    }
    #pragma unroll
    for (int qq = 0; qq < 4; ++qq) {
      U8 o;
      #pragma unroll
      for (int jj = 0; jj < 2; ++jj) {
        int col = cc * 32 + qq * 8 + jj * 4;
        float4 g = *(const float4*)&ze_bn1[col];
        float4 b = *(const float4*)&ze_bn1[128 + col];
        float4 m = *(const float4*)&ze_bn1[256 + col];
        float4 v = *(const float4*)&ze_bn1[384 + col];
        o.h[jj * 4 + 0] = f2b(fmaxf(0.f, bnf(acc[qq * 8 + jj * 4 + 0], g.x, b.x, m.x, v.x)));
        o.h[jj * 4 + 1] = f2b(fmaxf(0.f, bnf(acc[qq * 8 + jj * 4 + 1], g.y, b.y, m.y, v.y)));
        o.h[jj * 4 + 2] = f2b(fmaxf(0.f, bnf(acc[qq * 8 + jj * 4 + 2], g.z, b.z, m.z, v.z)));
        o.h[jj * 4 + 3] = f2b(fmaxf(0.f, bnf(acc[qq * 8 + jj * 4 + 3], g.w, b.w, m.w, v.w)));
      }
      *(uint4*)&Az[16 * wv + r][cc * 32 + qq * 8] = o.u;
    }
  }
  __builtin_amdgcn_wave_barrier();

  // ---- GEMM0: acc2 = EaB @ WeSw (K=32 incl. bias col)
  floatx4 acc2[8] = {};
  {
    short8 af0 = *(const short8*)&EaB[16 * wv + ln][q * 8];
    #pragma unroll
    for (int t = 0; t < 8; ++t) {
      short8 bfr = *(const short8*)(WeSw + ((size_t)t * 64 + lane) * 8);
      acc2[t] = __builtin_amdgcn_mfma_f32_16x16x32_bf16(af0, bfr, acc2[t], 0, 0, 0);
    }
  }
  // ---- GEMM1: acc1 = Az @ zeWsw
  floatx4 acc1[8] = {};
  #pragma unroll
  for (int kc = 0; kc < 4; ++kc) {
    short8 af = *(const short8*)&Az[16 * wv + ln][kc * 32 + q * 8];
    #pragma unroll
    for (int t = 0; t < 8; ++t) {
      short8 bfr = *(const short8*)(zeWsw + (((size_t)kc * 8 + t) * 64 + lane) * 8);
      acc1[t] = __builtin_amdgcn_mfma_f32_16x16x32_bf16(af, bfr, acc1[t], 0, 0, 0);
    }
  }
  // ---- z = relu(bn2(acc1 + ze_b)) -> own rows of Az (C-layout scatter)
  #pragma unroll
  for (int t = 0; t < 8; ++t) {
    int c = t * 16 + ln;
    float zb = ze_b[c];
    float gg = ze_bn2[c], bb = ze_bn2[128 + c], mm = ze_bn2[256 + c], vv = ze_bn2[384 + c];
    #pragma unroll
    for (int r = 0; r < 4; ++r)
      Az[16 * wv + q * 4 + r][c] = f2b(fmaxf(0.f, bnf(acc1[t][r] + zb, gg, bb, mm, vv)));
  }
  __builtin_amdgcn_wave_barrier();
  // ---- GEMM2: acc2 += Az(z) @ WpSw
  #pragma unroll
  for (int kc = 0; kc < 4; ++kc) {
    short8 af = *(const short8*)&Az[16 * wv + ln][kc * 32 + q * 8];
    #pragma unroll
    for (int t = 0; t < 8; ++t) {
      short8 bfr = *(const short8*)(WpSw + (((size_t)kc * 8 + t) * 64 + lane) * 8);
      acc2[t] = __builtin_amdgcn_mfma_f32_16x16x32_bf16(af, bfr, acc2[t], 0, 0, 0);
    }
  }
  // ---- epilogue: msg = relu(h_in[src] + acc2); agg[dst] += msg
  #pragma unroll
  for (int r = 0; r < 4; ++r) {
    int e = e0 + 16 * wv + q * 4 + r;
    int s = src[e], d2 = dst[e];
    #pragma unroll
    for (int t = 0; t < 8; ++t) {
      int c = t * 16 + ln;
      float val = acc2[t][r] + b2f(h_in[(size_t)s * Dd + c]);
      val = fmaxf(0.f, val);
      atomicAdd(&agg[(size_t)d2 * Dd + c], val);
    }
  }
}

// -------- fused node MLP, barrier-free MFMA version --------
__global__ __launch_bounds__(256) void k_mlp_fused(
    const bf16* __restrict__ h_in, const float* __restrict__ agg,
    const float* __restrict__ eps_arr, int l,
    const bf16* __restrict__ W1sw, const float* __restrict__ b1, const float* __restrict__ bn,
    const bf16* __restrict__ W2sw, const float* __restrict__ b2, const float* __restrict__ bnp,
    int is_last, bf16* __restrict__ out_b, float* __restrict__ out_f) {
  __shared__ bf16 R[4][16][280];   // wave-exclusive; x tile (cols 0..127), then t tile (0..255)
  int tid = threadIdx.x;
  int lane = tid & 63, wv = tid >> 6;
  int q = lane >> 4, ln = lane & 15;
  int r0 = blockIdx.x * 64;
  float epsv = 1.0f + eps_arr[l];
  // ---- stage x = (1+eps)*h_in + agg (bf16) into R[wv][0..15][0..127]
  {
    int r = lane >> 2, cc = lane & 3;
    int row = r0 + 16 * wv + r;
    #pragma unroll
    for (int u = 0; u < 4; ++u) {
      int cb = cc * 4 + u;             // uint4 index in 128-col row
      U8 o;
      if (row < Nn) {
        U8 hh; hh.u = ((const uint4*)h_in)[row * 16 + cb];
        float4 g0 = ((const float4*)agg)[row * 32 + cb * 2];
        float4 g1 = ((const float4*)agg)[row * 32 + cb * 2 + 1];
        o.h[0] = f2b(epsv * b2f(hh.h[0]) + g0.x); o.h[1] = f2b(epsv * b2f(hh.h[1]) + g0.y);
        o.h[2] = f2b(epsv * b2f(hh.h[2]) + g0.z); o.h[3] = f2b(epsv * b2f(hh.h[3]) + g0.w);
        o.h[4] = f2b(epsv * b2f(hh.h[4]) + g1.x); o.h[5] = f2b(epsv * b2f(hh.h[5]) + g1.y);
        o.h[6] = f2b(epsv * b2f(hh.h[6]) + g1.z); o.h[7] = f2b(epsv * b2f(hh.h[7]) + g1.w);
      } else {
        o.u.x = o.u.y = o.u.z = o.u.w = 0;
      }
      *(uint4*)&R[wv][r][cb * 8] = o.u;
    }
  }
  __builtin_amdgcn_wave_barrier();
  // ---- GEMM1: acc1[16] = x @ W1  (64x128 @ 128x256)
  floatx4 acc1[16] = {};
  #pragma unroll
  for (int kc = 0; kc < 4; ++kc) {
    short8 af = *(const short8*)&R[wv][ln][kc * 32 + q * 8];
    #pragma unroll
    for (int t = 0; t < 16; ++t) {
      short8 bfr = *(const short8*)(W1sw + (size_t)l * 32768 + (((size_t)kc * 16 + t) * 64 + lane) * 8);
      acc1[t] = __builtin_amdgcn_mfma_f32_16x16x32_bf16(af, bfr, acc1[t], 0, 0, 0);
    }
  }
  // ---- t = relu(bn(acc1 + b1)) -> R[wv] cols 0..255 (C-layout scatter)
  #pragma unroll
  for (int t = 0; t < 16; ++t) {
    int c = t * 16 + ln;
    float b1v = b1[c];
    float gg = bn[c], bb = bn[256 + c], mm = bn[512 + c], vv = bn[768 + c];
    #pragma unroll
    for (int r = 0; r < 4; ++r)
      R[wv][q * 4 + r][c] = f2b(fmaxf(0.f, bnf(acc1[t][r] + b1v, gg, bb, mm, vv)));
  }
  __builtin_amdgcn_wave_barrier();
  // ---- GEMM2: acc2[8] = t @ W2  (64x256 @ 256x128)
  floatx4 acc2[8] = {};
  #pragma unroll
  for (int kc = 0; kc < 8; ++kc) {
    short8 af = *(const short8*)&R[wv][ln][kc * 32 + q * 8];
    #pragma unroll
    for (int t = 0; t < 8; ++t) {
      short8 bfr = *(const short8*)(W2sw + (size_t)l * 32768 + (((size_t)kc * 8 + t) * 64 + lane) * 8);
      acc2[t] = __builtin_amdgcn_mfma_f32_16x16x32_bf16(af, bfr, acc2[t], 0, 0, 0);
    }
  }
  // ---- epilogue: out = bn2(acc2 + b2) [,relu]
  #pragma unroll
  for (int t = 0; t < 8; ++t) {
    int c = t * 16 + ln;
    float bv = b2[c];
    float gg = bnp[c], bb = bnp[128 + c], mm = bnp[256 + c], vv = bnp[384 + c];
    #pragma unroll
    for (int r = 0; r < 4; ++r) {
      int row = r0 + 16 * wv + q * 4 + r;
      if (row < Nn) {
        float x = bnf(acc2[t][r] + bv, gg, bb, mm, vv);
        if (is_last) out_f[(size_t)row * Dd + c] = x;
        else         out_b[(size_t)row * Dd + c] = f2b(fmaxf(0.f, x));
      }
    }
  }
}

// -------- vt = segment_sum(h_in, batch) --------
__global__ void k_vt_sum(const bf16* __restrict__ h_in, const int* __restrict__ batch,
                         float* __restrict__ vt) {
  int d = threadIdx.x;
  int chunk = (Nn + gridDim.x - 1) / gridDim.x;
  int r0 = blockIdx.x * chunk;
  int r1 = min(r0 + chunk, Nn);
  if (r0 >= r1) return;
  float acc = 0.f;
  int cur = batch[r0];
  for (int r = r0; r < r1; ++r) {
    int g = batch[r];
    if (g != cur) { atomicAdd(&vt[cur * Dd + d], acc); acc = 0.f; cur = g; }
    acc += b2f(h_in[r * Dd + d]);
  }
  atomicAdd(&vt[cur * Dd + d], acc);
}

// -------- virtual-node MLP (tiny) --------
__global__ __launch_bounds__(256) void k_vn_mlp(
    float* __restrict__ vn, const float* __restrict__ vt,
    const float* __restrict__ W1, const float* __restrict__ b1, const float* __restrict__ bn1,
    const float* __restrict__ W2, const float* __restrict__ b2, const float* __restrict__ bn2) {
  __shared__ float row[128];
  __shared__ float trow[256];
  int g = blockIdx.x;
  int tid = threadIdx.x;
  if (tid < 128) row[tid] = vt[g * Dd + tid] + vn[g * Dd + tid];
  __syncthreads();
  float acc = 0.f;
  for (int k = 0; k < 128; ++k) acc += row[k] * W1[k * 256 + tid];
  acc += b1[tid];
  trow[tid] = fmaxf(0.f, bnf(acc, bn1[tid], bn1[256 + tid], bn1[512 + tid], bn1[768 + tid]));
  __syncthreads();
  if (tid < 128) {
    float acc2 = 0.f;
    for (int k = 0; k < 256; ++k) acc2 += trow[k] * W2[k * Dd + tid];
    acc2 += b2[tid];
    vn[g * Dd + tid] = fmaxf(0.f, bnf(acc2, bn2[tid], bn2[128 + tid], bn2[256 + tid], bn2[384 + tid]));
  }
}

extern "C" void kernel_launch(void* const* d_in, const int* in_sizes, int n_in,
                              void* d_out, int out_size, void* d_ws, size_t ws_size,
                              hipStream_t stream) {
  const int*   x_node    = (const int*)  d_in[0];
  const int*   edge_idx  = (const int*)  d_in[1];
  const float* edge_attr = (const float*)d_in[2];
  const int*   batch     = (const int*)  d_in[3];
  const int*   pos_index = (const int*)  d_in[4];
  const float* pos_enc   = (const float*)d_in[5];
  const int*   pos_batch = (const int*)  d_in[6];
  const float* node_emb  = (const float*)d_in[7];
  const float* z_init    = (const float*)d_in[8];
  const float* ze_bn1    = (const float*)d_in[9];
  const float* ze_W      = (const float*)d_in[10];
  const float* ze_b      = (const float*)d_in[11];
  const float* ze_bn2    = (const float*)d_in[12];
  const float* vn_emb    = (const float*)d_in[13];
  const float* conv_We   = (const float*)d_in[14];
  const float* conv_be   = (const float*)d_in[15];
  const float* conv_Wp   = (const float*)d_in[16];
  const float* conv_bp   = (const float*)d_in[17];
  const float* conv_W1   = (const float*)d_in[18];
  const float* conv_b1   = (const float*)d_in[19];
  const float* conv_bn   = (const float*)d_in[20];
  const float* conv_W2   = (const float*)d_in[21];
  const float* conv_b2   = (const float*)d_in[22];
  const float* conv_eps  = (const float*)d_in[23];
  const float* layer_bn  = (const float*)d_in[24];
  const float* vn_W1     = (const float*)d_in[25];
  const float* vn_b1     = (const float*)d_in[26];
  const float* vn_bn1    = (const float*)d_in[27];
  const float* vn_W2     = (const float*)d_in[28];
  const float* vn_b2     = (const float*)d_in[29];
  const float* vn_bn2    = (const float*)d_in[30];

  // workspace (~80.0 MB)
  char* wb = (char*)d_ws;
  bf16*  h_in   = (bf16*)(wb);                      // N*128 bf16
  float* agg    = (float*)(wb + 25600000);          // N*128 f32
  float* vn     = (float*)(wb + 76800000);          // G*128 f32
  float* vt     = (float*)(wb + 76865536);          // G*128 f32
  int*   estart = (int*)  (wb + 76931072);          // (E+1) int
  bf16*  zeWsw  = (bf16*) (wb + 79491088);          // 16384 bf16
  bf16*  WpSw   = (bf16*) (wb + 79523856);          // 49152 bf16
  bf16*  WeSw   = (bf16*) (wb + 79622160);          // 12288 bf16
  bf16*  W1sw   = (bf16*) (wb + 79646736);          // 98304 bf16
  bf16*  W2sw   = (bf16*) (wb + 79843344);          // 98304 bf16
  // end ~80,039,952

  const int* src = edge_idx;
  const int* dst = edge_idx + Ee;

  k_estart<<<(Ee + 256) / 256, 256, 0, stream>>>(pos_batch, estart);
  k_prep<<<(98304 + 255) / 256, 256, 0, stream>>>(ze_W, conv_Wp, conv_We, conv_be, conv_bp,
                                                  conv_W1, conv_W2,
                                                  zeWsw, WpSw, WeSw, W1sw, W2sw);
  k_init_vn<<<(Gg * 128 + 255) / 256, 256, 0, stream>>>(vn_emb, vn);

  int hblocks = (Nn * 16 + 255) / 256;
  int mblocks = (Nn + 63) / 64;
  for (int l = 0; l < Ll; ++l) {
    if (l == 0) k_hin0<<<hblocks, 256, 0, stream>>>(x_node, node_emb, vn, batch, h_in);
    else        k_hin <<<hblocks, 256, 0, stream>>>(vn, batch, h_in);
    hipMemsetAsync(agg, 0, (size_t)Nn * 128 * 4, stream);
    k_edge_fused<<<Ee / 64, 256, 0, stream>>>(estart, pos_index, pos_enc, z_init,
        ze_bn1, zeWsw, ze_b, ze_bn2,
        edge_attr, src, dst, h_in,
        WpSw + (size_t)l * 16384, WeSw + (size_t)l * 4096, agg);
    if (l < Ll - 1) {
      hipMemsetAsync(vt, 0, (size_t)Gg * 128 * 4, stream);
      k_vt_sum<<<1024, 128, 0, stream>>>(h_in, batch, vt);
      k_vn_mlp<<<Gg, 256, 0, stream>>>(vn, vt,
          vn_W1 + (size_t)l * 128 * 256, vn_b1 + l * 256, vn_bn1 + (size_t)l * 4 * 256,
          vn_W2 + (size_t)l * 256 * 128, vn_b2 + l * 128, vn_bn2 + (size_t)l * 4 * 128);
    }
    k_mlp_fused<<<mblocks, 256, 0, stream>>>(h_in, agg, conv_eps, l,
        W1sw, conv_b1 + l * 256, conv_bn + (size_t)l * 4 * 256,
        W2sw, conv_b2 + l * 128, layer_bn + (size_t)l * 4 * 128,
        (l == Ll - 1) ? 1 : 0, h_in, (float*)d_out);
  }
}